// Round 2
// baseline (2051.662 us; speedup 1.0000x reference)
//
#include <hip/hip_runtime.h>

typedef unsigned short ushort_t;
typedef unsigned int uint_t;
typedef __bf16 bf16x8 __attribute__((ext_vector_type(8)));
typedef float f32x4 __attribute__((ext_vector_type(4)));

#define T_ 10
#define N_ 30000
#define F_ 256
#define H_ 128
#define L_ 5
#define YR_ 5
#define NSTEP 5
#define MROWS_ENC (T_*N_)      /* 300000 */
#define MROWS_GRU (YR_*N_)     /* 150000 */

/* ---- workspace layout (bytes) ---- */
#define OFF_EMB   ((size_t)0)
#define SZ_EMB    ((size_t)T_*N_*H_*2)          /* 76,800,000 */
#define OFF_WENC  (OFF_EMB + SZ_EMB)
#define SZ_WENC   ((size_t)F_*H_*2)             /* 65,536 */
#define OFF_WIH   (OFF_WENC + SZ_WENC)
#define SZ_W3H    ((size_t)H_*3*H_*2)           /* 98,304 */
#define OFF_WHH   (OFF_WIH + SZ_W3H)
#define OFF_ACC   (OFF_WHH + SZ_W3H)            /* 2 floats */

/* ---- helpers ---- */
__device__ __forceinline__ uint_t bfbits(float x){
    uint_t u = __float_as_uint(x);
    return (u + 0x7fffu + ((u >> 16) & 1u)) >> 16;   /* RNE f32->bf16 */
}
__device__ __forceinline__ uint_t pack2(float lo, float hi){
    return bfbits(lo) | (bfbits(hi) << 16);
}
__device__ __forceinline__ float unpk(uint_t u, int hi){
    return hi ? __uint_as_float(u & 0xffff0000u) : __uint_as_float(u << 16);
}
__device__ __forceinline__ f32x4 mfma16(bf16x8 a, bf16x8 b, f32x4 c){
    return __builtin_amdgcn_mfma_f32_16x16x32_bf16(a, b, c, 0, 0, 0);
}
__device__ __forceinline__ float fexp2_(float x){ return __builtin_amdgcn_exp2f(x); }
__device__ __forceinline__ float frcp_(float x){ return __builtin_amdgcn_rcpf(x); }
__device__ __forceinline__ float sigm_(float x){ return frcp_(1.f + fexp2_(-1.44269504f*x)); }
__device__ __forceinline__ float tanhfast_(float x){ return 1.f - 2.f*frcp_(1.f + fexp2_(2.88539008f*x)); }
__device__ __forceinline__ float softplus_(float x){
    float ax = fabsf(x);
    return fmaxf(x, 0.f) + log1pf(fexp2_(-1.44269504f*ax));
}
__device__ __forceinline__ float wave_sum(float v){
#pragma unroll
    for (int o = 32; o > 0; o >>= 1) v += __shfl_down(v, o, 64);
    return v;
}
union BU { uint4 u; bf16x8 v; };

/* ---- prep: transpose+convert weights to bf16, zero accumulators ---- */
__global__ void prep_kernel(const float* __restrict__ We, const float* __restrict__ Wih,
                            const float* __restrict__ Whh,
                            ushort_t* __restrict__ Wet, ushort_t* __restrict__ Wiht,
                            ushort_t* __restrict__ Whht, float* __restrict__ accv)
{
    int i = blockIdx.x * 256 + threadIdx.x;
    if (i < 2) accv[i] = 0.f;
    if (i < F_*H_){                       /* Wet[h][f] = We[f][h] */
        int h = i >> 8, f = i & 255;
        Wet[i] = (ushort_t)bfbits(We[f*H_ + h]);
    }
    if (i < 3*H_*H_){                     /* W*t[c][k] = W[k][c] */
        int c = i >> 7, k = i & 127;
        Wiht[i] = (ushort_t)bfbits(Wih[k*(3*H_) + c]);
        Whht[i] = (ushort_t)bfbits(Whh[k*(3*H_) + c]);
    }
}

/* ---- encoder: emb = relu(X @ W_enc). One barrier per 64-row tile.
   Wave wv owns output cols [wv*16, wv*16+16) via register-resident W^T frags. ---- */
#define XPITCH 264
__global__ __launch_bounds__(512, 4) void enc_kernel(const float* __restrict__ X,
                                                     const ushort_t* __restrict__ Wet,
                                                     ushort_t* __restrict__ emb)
{
    __shared__ __attribute__((aligned(16))) ushort_t Xs[64*XPITCH];
    const int tid = threadIdx.x;
    const int wv = tid >> 6, lane = tid & 63;
    const int m = lane & 15, q = lane >> 4;
    const int rowbase = blockIdx.x * 64;

    /* B-operand frags: W^T[col][k], col = wv*16 + m */
    bf16x8 wf[8];
    {
        const ushort_t* wp = Wet + (wv*16 + m)*F_ + q*8;
#pragma unroll
        for (int ks = 0; ks < 8; ++ks)
            wf[ks] = *reinterpret_cast<const bf16x8*>(wp + ks*32);
    }

    /* stage 64 rows x 256 cols f32 -> bf16 LDS (2 chunks of 16 f32 per thread) */
#pragma unroll
    for (int rep = 0; rep < 2; ++rep){
        int ci = rep*512 + tid;
        int r = ci >> 4, kc = ci & 15;
        int row = rowbase + r; if (row > MROWS_ENC - 1) row = MROWS_ENC - 1;
        const float* xs = X + (size_t)row * F_ + kc*16;
        float4 v0 = *(const float4*)(xs);
        float4 v1 = *(const float4*)(xs + 4);
        float4 v2 = *(const float4*)(xs + 8);
        float4 v3 = *(const float4*)(xs + 12);
        uint4 p0, p1;
        p0.x = pack2(v0.x, v0.y); p0.y = pack2(v0.z, v0.w);
        p0.z = pack2(v1.x, v1.y); p0.w = pack2(v1.z, v1.w);
        p1.x = pack2(v2.x, v2.y); p1.y = pack2(v2.z, v2.w);
        p1.z = pack2(v3.x, v3.y); p1.w = pack2(v3.z, v3.w);
        *(uint4*)&Xs[r*XPITCH + kc*16]     = p0;
        *(uint4*)&Xs[r*XPITCH + kc*16 + 8] = p1;
    }
    __syncthreads();

    f32x4 acc[4];
#pragma unroll
    for (int rt = 0; rt < 4; ++rt) acc[rt] = (f32x4){0.f,0.f,0.f,0.f};
#pragma unroll
    for (int ks = 0; ks < 8; ++ks){
#pragma unroll
        for (int rt = 0; rt < 4; ++rt){
            bf16x8 a = *reinterpret_cast<const bf16x8*>(&Xs[(rt*16 + m)*XPITCH + ks*32 + q*8]);
            acc[rt] = mfma16(a, wf[ks], acc[rt]);
        }
    }
    /* D: row = rt*16 + q*4 + i (X row), col = wv*16 + m */
#pragma unroll
    for (int rt = 0; rt < 4; ++rt)
#pragma unroll
        for (int i = 0; i < 4; ++i){
            int row = rowbase + rt*16 + q*4 + i;
            if (row < MROWS_ENC){
                float v = acc[rt][i];
                v = v > 0.f ? v : 0.f;
                emb[(size_t)row * H_ + wv*16 + m] = (ushort_t)bfbits(v);
            }
        }
}

/* ---- l_time ---- */
__global__ __launch_bounds__(256) void ltime_kernel(const ushort_t* __restrict__ emb,
                                                    float* __restrict__ accv)
{
    const int g = blockIdx.x * 256 + threadIdx.x;
    const int base = g * 8;
    float s = 0.f;
    uint4 pv = *(const uint4*)(emb + base);
#pragma unroll
    for (int t = 1; t < T_; ++t){
        uint4 cv = *(const uint4*)(emb + (size_t)t * N_ * H_ + base);
        const uint_t pa[4] = {pv.x, pv.y, pv.z, pv.w};
        const uint_t ca[4] = {cv.x, cv.y, cv.z, cv.w};
#pragma unroll
        for (int j = 0; j < 4; ++j){
            float al = __uint_as_float(pa[j] << 16), ah = __uint_as_float(pa[j] & 0xffff0000u);
            float bl = __uint_as_float(ca[j] << 16), bh = __uint_as_float(ca[j] & 0xffff0000u);
            float d0 = al - bl, d1 = ah - bh;
            s += d0*d0 + d1*d1;
        }
        pv = cv;
    }
    s = wave_sum(s);
    __shared__ float red[4];
    const int lane = threadIdx.x & 63, wv = threadIdx.x >> 6;
    if (lane == 0) red[wv] = s;
    __syncthreads();
    if (threadIdx.x == 0) atomicAdd(&accv[0], red[0] + red[1] + red[2] + red[3]);
}

/* ---- GRU (transposed, wave-private recurrence) + heads + loss ----
   Wave owns 16 batch rows. gh^T = A(W^T from LDS) x B(h^T in regs).
   C-layout out: gate-col = ct*16 + q*4 + reg, batch row n = lane&15.
   No __syncthreads after weight staging. */
#define WPITCH 136
__global__ __launch_bounds__(1024, 4) void gru_kernel(const ushort_t* __restrict__ emb,
                                                      const ushort_t* __restrict__ Wiht,
                                                      const ushort_t* __restrict__ Whht,
                                                      const float* __restrict__ bih,
                                                      const float* __restrict__ bhh,
                                                      const float* __restrict__ Wheads,
                                                      const float* __restrict__ bheads,
                                                      const float* __restrict__ Yv,
                                                      const int* __restrict__ years,
                                                      float* __restrict__ accv)
{
    __shared__ __attribute__((aligned(16))) ushort_t Wl[384*WPITCH]; /* 104448 B */
    __shared__ __attribute__((aligned(16))) float bsum[384];  /* r,z: bih+bhh; n: bih */
    __shared__ __attribute__((aligned(16))) float bh2s[128];  /* bhh n-gate */
    __shared__ __attribute__((aligned(16))) float whl[384];   /* W_heads [c][3] */
    const int tid = threadIdx.x;
    const int lane = tid & 63;
    const int nn_ = lane & 15, q = lane >> 4;
    const int wv = tid >> 6;
    const int rowbase = blockIdx.x * 256 + wv * 16;

    if (tid < 384){
        float b = bih[tid];
        if (tid < 256) b += bhh[tid];
        bsum[tid] = b;
        whl[tid] = Wheads[tid];
    } else if (tid < 512){
        bh2s[tid - 384] = bhh[256 + (tid - 384)];
    }
    /* stage W_ih^T: 384 rows x 128 k, 16-elem chunks */
#pragma unroll
    for (int r = 0; r < 6; ++r){
        int ci = r*1024 + tid;
        int c = ci >> 4, kc = ci & 15;
        uint4 d = *(const uint4*)(Wiht + c*H_ + kc*8);
        *(uint4*)&Wl[c*WPITCH + kc*8] = d;
    }
    /* v B-frags from emb (gather) */
    const int gr_raw = rowbase + nn_;
    int gr = gr_raw; if (gr > MROWS_GRU - 1) gr = MROWS_GRU - 1;
    const int yy = gr / N_;
    const int n0 = gr - yy * N_;
    const int yr = years[yy];
    const ushort_t* vrow = emb + (size_t)(yr*N_ + n0) * H_;
    bf16x8 hfrag[4];
#pragma unroll
    for (int ks = 0; ks < 4; ++ks)
        hfrag[ks] = *reinterpret_cast<const bf16x8*>(vrow + ks*32 + q*8);
    __syncthreads();

    /* gx^T = W_ih^T @ v^T (+ folded biases), stored packed bf16 */
    uint_t gxpk[24][2];
#pragma unroll
    for (int ct = 0; ct < 24; ++ct){
        f32x4 acc = (f32x4){0.f,0.f,0.f,0.f};
#pragma unroll
        for (int ks = 0; ks < 4; ++ks){
            bf16x8 a = *reinterpret_cast<const bf16x8*>(&Wl[(ct*16 + nn_)*WPITCH + ks*32 + q*8]);
            acc = mfma16(a, hfrag[ks], acc);
        }
        f32x4 bs = *(const f32x4*)&bsum[ct*16 + q*4];
        acc += bs;
        gxpk[ct][0] = pack2(acc[0], acc[1]);
        gxpk[ct][1] = pack2(acc[2], acc[3]);
    }
    __syncthreads();
    /* stage W_hh^T over the same LDS */
#pragma unroll
    for (int r = 0; r < 6; ++r){
        int ci = r*1024 + tid;
        int c = ci >> 4, kc = ci & 15;
        uint4 d = *(const uint4*)(Whht + c*H_ + kc*8);
        *(uint4*)&Wl[c*WPITCH + kc*8] = d;
    }
    __syncthreads();
    /* ---- barrier-free from here on ---- */

    uint_t hpk[8][2];
    /* step 0: h0 = 0 */
#pragma unroll
    for (int ct = 0; ct < 8; ++ct){
        f32x4 bh2v = *(const f32x4*)&bh2s[ct*16 + q*4];
        float hv[4];
#pragma unroll
        for (int i = 0; i < 4; ++i){
            float xr = unpk(gxpk[ct][i>>1],    i&1);
            float xz = unpk(gxpk[8+ct][i>>1],  i&1);
            float xn = unpk(gxpk[16+ct][i>>1], i&1);
            float r_ = sigm_(xr);
            float z_ = sigm_(xz);
            float t_ = tanhfast_(xn + r_ * bh2v[i]);
            hv[i] = (1.f - z_) * t_;
        }
        hpk[ct][0] = pack2(hv[0], hv[1]);
        hpk[ct][1] = pack2(hv[2], hv[3]);
    }

    const int srcA = nn_ + (((2*q)   & 3) << 4);
    const int srcB = nn_ + (((2*q+1) & 3) << 4);
    const bool lowq = (q < 2);

#pragma unroll 1
    for (int step = 1; step < NSTEP; ++step){
        /* rebuild B-layout h frags from C-layout hpk (wave-local shuffles) */
#pragma unroll
        for (int ks = 0; ks < 4; ++ks){
            uint_t a0 = hpk[2*ks][0],   a1 = hpk[2*ks][1];
            uint_t b0 = hpk[2*ks+1][0], b1 = hpk[2*ks+1][1];
            uint_t A0 = __shfl(a0, srcA), B0 = __shfl(b0, srcA);
            uint_t A1 = __shfl(a1, srcA), B1 = __shfl(b1, srcA);
            uint_t A2 = __shfl(a0, srcB), B2 = __shfl(b0, srcB);
            uint_t A3 = __shfl(a1, srcB), B3 = __shfl(b1, srcB);
            BU t;
            t.u.x = lowq ? A0 : B0;
            t.u.y = lowq ? A1 : B1;
            t.u.z = lowq ? A2 : B2;
            t.u.w = lowq ? A3 : B3;
            hfrag[ks] = t.v;
        }
#pragma unroll
        for (int ct = 0; ct < 8; ++ct){
            f32x4 ar = (f32x4){0.f,0.f,0.f,0.f};
            f32x4 az = (f32x4){0.f,0.f,0.f,0.f};
            f32x4 an = (f32x4){0.f,0.f,0.f,0.f};
#pragma unroll
            for (int ks = 0; ks < 4; ++ks){
                bf16x8 wa = *reinterpret_cast<const bf16x8*>(&Wl[(ct*16      + nn_)*WPITCH + ks*32 + q*8]);
                bf16x8 wb = *reinterpret_cast<const bf16x8*>(&Wl[((8+ct)*16  + nn_)*WPITCH + ks*32 + q*8]);
                bf16x8 wc = *reinterpret_cast<const bf16x8*>(&Wl[((16+ct)*16 + nn_)*WPITCH + ks*32 + q*8]);
                ar = mfma16(wa, hfrag[ks], ar);
                az = mfma16(wb, hfrag[ks], az);
                an = mfma16(wc, hfrag[ks], an);
            }
            f32x4 bh2v = *(const f32x4*)&bh2s[ct*16 + q*4];
            float hv[4];
#pragma unroll
            for (int i = 0; i < 4; ++i){
                float xr = unpk(gxpk[ct][i>>1],    i&1);
                float xz = unpk(gxpk[8+ct][i>>1],  i&1);
                float xn = unpk(gxpk[16+ct][i>>1], i&1);
                float r_ = sigm_(xr + ar[i]);
                float z_ = sigm_(xz + az[i]);
                float t_ = tanhfast_(xn + r_ * (an[i] + bh2v[i]));
                float ho = unpk(hpk[ct][i>>1], i&1);
                hv[i] = t_ + z_ * (ho - t_);
            }
            hpk[ct][0] = pack2(hv[0], hv[1]);
            hpk[ct][1] = pack2(hv[2], hv[3]);
        }
    }

    /* heads: per-lane partial dots over its 32 h elements, reduce across quads */
    float a0 = 0.f, a1 = 0.f, a2 = 0.f;
#pragma unroll
    for (int ct = 0; ct < 8; ++ct)
#pragma unroll
        for (int i = 0; i < 4; ++i){
            float hv = unpk(hpk[ct][i>>1], i&1);
            int c = ct*16 + q*4 + i;
            a0 += hv * whl[c*3 + 0];
            a1 += hv * whl[c*3 + 1];
            a2 += hv * whl[c*3 + 2];
        }
    a0 += __shfl_xor(a0, 16, 64); a0 += __shfl_xor(a0, 32, 64);
    a1 += __shfl_xor(a1, 16, 64); a1 += __shfl_xor(a1, 32, 64);
    a2 += __shfl_xor(a2, 16, 64); a2 += __shfl_xor(a2, 32, 64);

    float loss = 0.f;
    if (q == 0 && gr_raw < MROWS_GRU){
        float eta = softplus_(a0 + bheads[0]);
        float mu  = a1 + bheads[1];
        float sg  = softplus_(a2 + bheads[2]) + 1e-3f;
        float inv = frcp_(sg);
        const float LH[5] = {0.f, 0.69314718f, 1.09861229f, 1.38629436f, 1.60943791f};
        const float* yrow = Yv + ((size_t)(yr*N_ + n0)) * L_;
        float prev = 0.f;
#pragma unroll
        for (int l = 0; l < L_; ++l){
            float zz  = (LH[l] - mu) * inv;
            float cdf = 0.5f * erfcf(-zz * 0.70710678f);
            float yc  = eta * cdf;
            float yh  = yc - prev; prev = yc;
            float d   = log1pf(yrow[l] + 1.0f) - log1pf(yh);
            loss += d * d;
        }
    }
    loss = wave_sum(loss);
    if (lane == 0) atomicAdd(&accv[1], loss);
}

/* ---- finalize ---- */
__global__ void fin_kernel(const float* __restrict__ accv, float* __restrict__ out)
{
    out[0] = accv[1] * (1.f / (float)(YR_*N_*L_)) +
             1e-3f * accv[0] * (1.f / (float)((T_-1)*N_));
}

extern "C" void kernel_launch(void* const* d_in, const int* in_sizes, int n_in,
                              void* d_out, int out_size, void* d_ws, size_t ws_size,
                              hipStream_t stream)
{
    (void)in_sizes; (void)n_in; (void)out_size; (void)ws_size;
    const float* X       = (const float*)d_in[0];
    const float* W_enc   = (const float*)d_in[1];
    const float* W_ih    = (const float*)d_in[2];
    const float* W_hh    = (const float*)d_in[3];
    const float* b_ih    = (const float*)d_in[4];
    const float* b_hh    = (const float*)d_in[5];
    const float* W_heads = (const float*)d_in[6];
    const float* b_heads = (const float*)d_in[7];
    const float* Yv      = (const float*)d_in[8];
    const int*   years   = (const int*)d_in[9];

    char* ws = (char*)d_ws;
    ushort_t* emb  = (ushort_t*)(ws + OFF_EMB);
    ushort_t* Wet  = (ushort_t*)(ws + OFF_WENC);
    ushort_t* Wiht = (ushort_t*)(ws + OFF_WIH);
    ushort_t* Whht = (ushort_t*)(ws + OFF_WHH);
    float*    accv = (float*)(ws + OFF_ACC);

    prep_kernel<<<192, 256, 0, stream>>>(W_enc, W_ih, W_hh, Wet, Wiht, Whht, accv);
    enc_kernel<<<(MROWS_ENC + 63)/64, 512, 0, stream>>>(X, Wet, emb);
    ltime_kernel<<<(N_*16)/256, 256, 0, stream>>>(emb, accv);
    gru_kernel<<<(MROWS_GRU + 255)/256, 1024, 0, stream>>>(emb, Wiht, Whht, b_ih, b_hh,
                                                           W_heads, b_heads, Yv, years, accv);
    fin_kernel<<<1, 1, 0, stream>>>(accv, (float*)d_out);
}

// Round 3
// 988.781 us; speedup vs baseline: 2.0749x; 2.0749x over previous
//
#include <hip/hip_runtime.h>

typedef unsigned short ushort_t;
typedef unsigned int uint_t;
typedef __bf16 bf16x8 __attribute__((ext_vector_type(8)));
typedef float f32x4 __attribute__((ext_vector_type(4)));

#define T_ 10
#define N_ 30000
#define F_ 256
#define H_ 128
#define L_ 5
#define YR_ 5
#define NSTEP 5
#define MROWS_GRU (YR_*N_)     /* 150000 */

/* ---- workspace layout (bytes) ---- */
#define OFF_EMB   ((size_t)0)
#define SZ_EMB    ((size_t)T_*N_*H_*2)          /* 76,800,000 */
#define OFF_WENC  (OFF_EMB + SZ_EMB)
#define SZ_WENC   ((size_t)F_*H_*2)
#define OFF_WIH   (OFF_WENC + SZ_WENC)
#define SZ_W3H    ((size_t)H_*3*H_*2)
#define OFF_WHH   (OFF_WIH + SZ_W3H)
#define OFF_ACC   (OFF_WHH + SZ_W3H)            /* 2 floats: [0]=l_time, [1]=l_pred */

/* ---- helpers ---- */
__device__ __forceinline__ uint_t bfbits(float x){
    uint_t u = __float_as_uint(x);
    return (u + 0x7fffu + ((u >> 16) & 1u)) >> 16;   /* RNE f32->bf16 */
}
__device__ __forceinline__ uint_t pack2(float lo, float hi){
    return bfbits(lo) | (bfbits(hi) << 16);
}
__device__ __forceinline__ float unpk(uint_t u, int hi){
    return hi ? __uint_as_float(u & 0xffff0000u) : __uint_as_float(u << 16);
}
__device__ __forceinline__ f32x4 mfma16(bf16x8 a, bf16x8 b, f32x4 c){
    return __builtin_amdgcn_mfma_f32_16x16x32_bf16(a, b, c, 0, 0, 0);
}
__device__ __forceinline__ float fexp2_(float x){ return __builtin_amdgcn_exp2f(x); }
__device__ __forceinline__ float frcp_(float x){ return __builtin_amdgcn_rcpf(x); }
__device__ __forceinline__ float sigm_(float x){ return frcp_(1.f + fexp2_(-1.44269504f*x)); }
__device__ __forceinline__ float tanhfast_(float x){ return 1.f - 2.f*frcp_(1.f + fexp2_(2.88539008f*x)); }
__device__ __forceinline__ float softplus_(float x){
    float ax = fabsf(x);
    return fmaxf(x, 0.f) + log1pf(fexp2_(-1.44269504f*ax));
}
__device__ __forceinline__ float wave_sum(float v){
#pragma unroll
    for (int o = 32; o > 0; o >>= 1) v += __shfl_down(v, o, 64);
    return v;
}
union BU { uint4 u; bf16x8 v; };

/* ---- prep: transpose+convert weights to bf16, zero accumulators ---- */
__global__ void prep_kernel(const float* __restrict__ We, const float* __restrict__ Wih,
                            const float* __restrict__ Whh,
                            ushort_t* __restrict__ Wet, ushort_t* __restrict__ Wiht,
                            ushort_t* __restrict__ Whht, float* __restrict__ accv)
{
    int i = blockIdx.x * 256 + threadIdx.x;
    if (i < 2) accv[i] = 0.f;
    if (i < F_*H_){                       /* Wet[h][f] = We[f][h] */
        int h = i >> 8, f = i & 255;
        Wet[i] = (ushort_t)bfbits(We[f*H_ + h]);
    }
    if (i < 3*H_*H_){                     /* W*t[c][k] = W[k][c] */
        int c = i >> 7, k = i & 127;
        Wiht[i] = (ushort_t)bfbits(Wih[k*(3*H_) + c]);
        Whht[i] = (ushort_t)bfbits(Whh[k*(3*H_) + c]);
    }
}

/* ---- encoder + fused l_time: block owns 32 papers across all T snapshots ----
   A = X rows (LDS), B = W^T cols (registers, wave wv owns cols wv*16..+16).
   C element: X-row = rt*16+q*4+i, col = wv*16+m. */
#define XP 264   /* Xs pitch (ushorts), rows 528 B (16-B aligned) */
#define CP 136   /* Cs pitch, rows 272 B */
__global__ __launch_bounds__(512, 4) void enc_kernel(const float* __restrict__ X,
                                                     const ushort_t* __restrict__ Wet,
                                                     ushort_t* __restrict__ emb,
                                                     float* __restrict__ accv)
{
    __shared__ __attribute__((aligned(16))) ushort_t Xs[32][XP];
    __shared__ __attribute__((aligned(16))) ushort_t Cs[32][CP];
    const int tid = threadIdx.x;
    const int wv = tid >> 6, lane = tid & 63;
    const int m = lane & 15, q = lane >> 4;
    const int nb = blockIdx.x * 32;

    /* B-frags: W^T[col][k], col = wv*16+m */
    bf16x8 wb[8];
#pragma unroll
    for (int ks = 0; ks < 8; ++ks)
        wb[ks] = *reinterpret_cast<const bf16x8*>(Wet + (wv*16 + m)*F_ + ks*32 + q*8);

    /* staging coords */
    const int sr = tid >> 4, kc4 = tid & 15;
    int srow = nb + sr; if (srow > N_-1) srow = N_-1;
    const bool st_ok = (nb + sr) < N_;

    float prev[2][4];
    float ltacc = 0.f;
    bool valid[2][4];
#pragma unroll
    for (int rt = 0; rt < 2; ++rt)
#pragma unroll
        for (int i = 0; i < 4; ++i)
            valid[rt][i] = (nb + rt*16 + q*4 + i) < N_;

    for (int t = 0; t < T_; ++t){
        /* stage X[t] rows -> bf16 LDS (unit-stride loads per instruction) */
        {
            const float* xp = X + ((size_t)t*N_ + srow)*F_;
#pragma unroll
            for (int j = 0; j < 4; ++j){
                float4 v = *(const float4*)(xp + j*64 + kc4*4);
                uint2 w; w.x = pack2(v.x, v.y); w.y = pack2(v.z, v.w);
                *(uint2*)&Xs[sr][j*64 + kc4*4] = w;
            }
        }
        __syncthreads();

        f32x4 acc[2];
        acc[0] = (f32x4){0.f,0.f,0.f,0.f};
        acc[1] = (f32x4){0.f,0.f,0.f,0.f};
#pragma unroll
        for (int ks = 0; ks < 8; ++ks){
#pragma unroll
            for (int rt = 0; rt < 2; ++rt){
                bf16x8 a = *reinterpret_cast<const bf16x8*>(&Xs[rt*16 + m][ks*32 + q*8]);
                acc[rt] = mfma16(a, wb[ks], acc[rt]);
            }
        }
        /* relu, l_time, transpose to Cs */
#pragma unroll
        for (int rt = 0; rt < 2; ++rt)
#pragma unroll
            for (int i = 0; i < 4; ++i){
                float v = acc[rt][i] > 0.f ? acc[rt][i] : 0.f;
                if (t > 0 && valid[rt][i]){
                    float d = prev[rt][i] - v;
                    ltacc += d*d;
                }
                prev[rt][i] = v;
                Cs[rt*16 + q*4 + i][wv*16 + m] = (ushort_t)bfbits(v);
            }
        __syncthreads();
        /* coalesced store pass: thread -> 16 B of one row */
        if (st_ok){
            uint4 d = *(uint4*)&Cs[sr][kc4*8];
            *(uint4*)(emb + ((size_t)t*N_ + nb + sr)*H_ + kc4*8) = d;
        }
        /* next t's first barrier separates Cs reads here from next Cs writes */
    }
    ltacc = wave_sum(ltacc);
    if (lane == 0) atomicAdd(&accv[0], ltacc);
}

/* ---- GRU + heads + loss: block owns 32 batch rows, weights in registers ----
   gh^T = A(W^T slice, regs) x B(h^T, LDS double-buffered).
   Wave wv owns h-dims [wv*16, wv*16+16) for all 3 gates.
   C element: dim = wv*16+q*4+i, n = nt*16 + m.  1 barrier per step. */
#define HP 136
__global__ __launch_bounds__(512, 2) void gru_kernel(const ushort_t* __restrict__ emb,
                                                     const ushort_t* __restrict__ Wiht,
                                                     const ushort_t* __restrict__ Whht,
                                                     const float* __restrict__ bih,
                                                     const float* __restrict__ bhh,
                                                     const float* __restrict__ Wheads,
                                                     const float* __restrict__ bheads,
                                                     const float* __restrict__ Yv,
                                                     const int* __restrict__ years,
                                                     float* __restrict__ accv)
{
    __shared__ __attribute__((aligned(16))) ushort_t Hs[2][32][HP];
    __shared__ float whl[3*H_];
    const int tid = threadIdx.x;
    const int wv = tid >> 6, lane = tid & 63;
    const int m = lane & 15, q = lane >> 4;
    const int rb = blockIdx.x * 32;

    if (tid < 3*H_) whl[tid] = Wheads[tid];

    /* stage v tile (gathered rows of emb): 32 rows x 128, coalesced */
    {
        int r = tid >> 4, kc = tid & 15;
        int grow = rb + r; if (grow > MROWS_GRU-1) grow = MROWS_GRU-1;
        int yy = grow / N_;
        int n0 = grow - yy*N_;
        int yr = years[yy];
        uint4 d = *(const uint4*)(emb + ((size_t)(yr*N_ + n0))*H_ + kc*8);
        *(uint4*)&Hs[0][r][kc*8] = d;
    }

    /* A-frags: W_ih^T rows {g*128 + wv*16 + m} */
    bf16x8 wa[3][4];
#pragma unroll
    for (int g = 0; g < 3; ++g)
#pragma unroll
        for (int ks = 0; ks < 4; ++ks)
            wa[g][ks] = *reinterpret_cast<const bf16x8*>(
                Wiht + (size_t)(g*H_ + wv*16 + m)*H_ + ks*32 + q*8);

    /* per-lane biases for dims d = wv*16 + q*4 + i */
    const int dbase = wv*16 + q*4;
    float bsr[4], bsz[4], bxn[4], bhn[4];
#pragma unroll
    for (int i = 0; i < 4; ++i){
        bsr[i] = bih[dbase+i]        + bhh[dbase+i];
        bsz[i] = bih[H_+dbase+i]     + bhh[H_+dbase+i];
        bxn[i] = bih[2*H_+dbase+i];
        bhn[i] = bhh[2*H_+dbase+i];
    }
    __syncthreads();

    /* gx^T = W_ih^T @ v^T (+folded biases), packed bf16 */
    bf16x8 Bv[2][4];
#pragma unroll
    for (int nt = 0; nt < 2; ++nt)
#pragma unroll
        for (int ks = 0; ks < 4; ++ks)
            Bv[nt][ks] = *reinterpret_cast<const bf16x8*>(&Hs[0][nt*16 + m][ks*32 + q*8]);

    uint_t gxpk[3][2][2];
#pragma unroll
    for (int g = 0; g < 3; ++g)
#pragma unroll
        for (int nt = 0; nt < 2; ++nt){
            f32x4 acc = (f32x4){0.f,0.f,0.f,0.f};
#pragma unroll
            for (int ks = 0; ks < 4; ++ks)
                acc = mfma16(wa[g][ks], Bv[nt][ks], acc);
#pragma unroll
            for (int i = 0; i < 4; ++i)
                acc[i] += (g == 0) ? bsr[i] : (g == 1) ? bsz[i] : bxn[i];
            gxpk[g][nt][0] = pack2(acc[0], acc[1]);
            gxpk[g][nt][1] = pack2(acc[2], acc[3]);
        }

    /* swap register weights to W_hh^T */
#pragma unroll
    for (int g = 0; g < 3; ++g)
#pragma unroll
        for (int ks = 0; ks < 4; ++ks)
            wa[g][ks] = *reinterpret_cast<const bf16x8*>(
                Whht + (size_t)(g*H_ + wv*16 + m)*H_ + ks*32 + q*8);

    /* step 0 (h=0, gh = bhh only) */
    uint_t hpk[2][2];
#pragma unroll
    for (int nt = 0; nt < 2; ++nt){
        float hv[4];
#pragma unroll
        for (int i = 0; i < 4; ++i){
            float xr = unpk(gxpk[0][nt][i>>1], i&1);
            float xz = unpk(gxpk[1][nt][i>>1], i&1);
            float xn = unpk(gxpk[2][nt][i>>1], i&1);
            float r_ = sigm_(xr);
            float z_ = sigm_(xz);
            float t_ = tanhfast_(xn + r_ * bhn[i]);
            hv[i] = (1.f - z_) * t_;
        }
        hpk[nt][0] = pack2(hv[0], hv[1]);
        hpk[nt][1] = pack2(hv[2], hv[3]);
        *(uint2*)&Hs[1][nt*16 + m][wv*16 + q*4] = *(uint2*)&hpk[nt][0];
    }
    __syncthreads();

    /* steps 1..4: rd = s&1, wr = (s+1)&1; one barrier per step */
#pragma unroll
    for (int s = 1; s < NSTEP; ++s){
        const int rd = s & 1, wr = (s + 1) & 1;
#pragma unroll
        for (int nt = 0; nt < 2; ++nt)
#pragma unroll
            for (int ks = 0; ks < 4; ++ks)
                Bv[nt][ks] = *reinterpret_cast<const bf16x8*>(&Hs[rd][nt*16 + m][ks*32 + q*8]);
#pragma unroll
        for (int nt = 0; nt < 2; ++nt){
            f32x4 ar = (f32x4){0.f,0.f,0.f,0.f};
            f32x4 az = (f32x4){0.f,0.f,0.f,0.f};
            f32x4 an = (f32x4){0.f,0.f,0.f,0.f};
#pragma unroll
            for (int ks = 0; ks < 4; ++ks){
                ar = mfma16(wa[0][ks], Bv[nt][ks], ar);
                az = mfma16(wa[1][ks], Bv[nt][ks], az);
                an = mfma16(wa[2][ks], Bv[nt][ks], an);
            }
            float hv[4];
#pragma unroll
            for (int i = 0; i < 4; ++i){
                float xr = unpk(gxpk[0][nt][i>>1], i&1);
                float xz = unpk(gxpk[1][nt][i>>1], i&1);
                float xn = unpk(gxpk[2][nt][i>>1], i&1);
                float r_ = sigm_(xr + ar[i]);
                float z_ = sigm_(xz + az[i]);
                float t_ = tanhfast_(xn + r_ * (an[i] + bhn[i]));
                float ho = unpk(hpk[nt][i>>1], i&1);
                hv[i] = t_ + z_ * (ho - t_);
            }
            hpk[nt][0] = pack2(hv[0], hv[1]);
            hpk[nt][1] = pack2(hv[2], hv[3]);
            *(uint2*)&Hs[wr][nt*16 + m][wv*16 + q*4] = *(uint2*)&hpk[nt][0];
        }
        __syncthreads();
    }

    /* heads + loss: h_last in Hs[1]; 16 threads per row */
    {
        const int r = tid >> 4, p = tid & 15;
        BU hb; hb.u = *(uint4*)&Hs[1][r][p*8];
        float a0 = 0.f, a1 = 0.f, a2 = 0.f;
#pragma unroll
        for (int k = 0; k < 8; ++k){
            float hv = (float)hb.v[k];
            const float* w = &whl[(p*8 + k)*3];
            a0 += hv * w[0];
            a1 += hv * w[1];
            a2 += hv * w[2];
        }
#pragma unroll
        for (int s = 1; s < 16; s <<= 1){
            a0 += __shfl_xor(a0, s, 64);
            a1 += __shfl_xor(a1, s, 64);
            a2 += __shfl_xor(a2, s, 64);
        }
        float loss = 0.f;
        const int grow = rb + r;
        if (p == 0 && grow < MROWS_GRU){
            int yy = grow / N_;
            int n0 = grow - yy*N_;
            int yr = years[yy];
            float eta = softplus_(a0 + bheads[0]);
            float mu  = a1 + bheads[1];
            float sg  = softplus_(a2 + bheads[2]) + 1e-3f;
            float inv = frcp_(sg);
            const float LH[5] = {0.f, 0.69314718f, 1.09861229f, 1.38629436f, 1.60943791f};
            const float* yrow = Yv + ((size_t)(yr*N_ + n0)) * L_;
            float prev = 0.f;
#pragma unroll
            for (int l = 0; l < L_; ++l){
                float zz  = (LH[l] - mu) * inv;
                float cdf = 0.5f * erfcf(-zz * 0.70710678f);
                float yc  = eta * cdf;
                float yh  = yc - prev; prev = yc;
                float d   = log1pf(yrow[l] + 1.0f) - log1pf(yh);
                loss += d * d;
            }
        }
        loss = wave_sum(loss);
        if (lane == 0) atomicAdd(&accv[1], loss);
    }
}

/* ---- finalize ---- */
__global__ void fin_kernel(const float* __restrict__ accv, float* __restrict__ out)
{
    out[0] = accv[1] * (1.f / (float)(YR_*N_*L_)) +
             1e-3f * accv[0] * (1.f / (float)((T_-1)*N_));
}

extern "C" void kernel_launch(void* const* d_in, const int* in_sizes, int n_in,
                              void* d_out, int out_size, void* d_ws, size_t ws_size,
                              hipStream_t stream)
{
    (void)in_sizes; (void)n_in; (void)out_size; (void)ws_size;
    const float* X       = (const float*)d_in[0];
    const float* W_enc   = (const float*)d_in[1];
    const float* W_ih    = (const float*)d_in[2];
    const float* W_hh    = (const float*)d_in[3];
    const float* b_ih    = (const float*)d_in[4];
    const float* b_hh    = (const float*)d_in[5];
    const float* W_heads = (const float*)d_in[6];
    const float* b_heads = (const float*)d_in[7];
    const float* Yv      = (const float*)d_in[8];
    const int*   years   = (const int*)d_in[9];

    char* ws = (char*)d_ws;
    ushort_t* emb  = (ushort_t*)(ws + OFF_EMB);
    ushort_t* Wet  = (ushort_t*)(ws + OFF_WENC);
    ushort_t* Wiht = (ushort_t*)(ws + OFF_WIH);
    ushort_t* Whht = (ushort_t*)(ws + OFF_WHH);
    float*    accv = (float*)(ws + OFF_ACC);

    prep_kernel<<<192, 256, 0, stream>>>(W_enc, W_ih, W_hh, Wet, Wiht, Whht, accv);
    enc_kernel<<<(N_ + 31)/32, 512, 0, stream>>>(X, Wet, emb, accv);
    gru_kernel<<<(MROWS_GRU + 31)/32, 512, 0, stream>>>(emb, Wiht, Whht, b_ih, b_hh,
                                                        W_heads, b_heads, Yv, years, accv);
    fin_kernel<<<1, 1, 0, stream>>>(accv, (float*)d_out);
}